// Round 2
// baseline (8916.251 us; speedup 1.0000x reference)
//
#include <hip/hip_runtime.h>

// Sizes: B=256, T=1024, H=512, IN=OUT=2
// Phase 1 decomposition: 16 batch-groups x 16 col-slices, 1 wg (128 thr) per
// (group, slice); each WAVE owns 16 h-cols x 3 gates, fully self-contained:
// no LDS, no __syncthreads in the step loop. Exchange via IF$-coherent (sc1)
// loads/stores + per-wave monotonic flags.

typedef short bf16x8 __attribute__((ext_vector_type(8)));
typedef float f32x4  __attribute__((ext_vector_type(4)));

__device__ __forceinline__ unsigned f2bf(float f) {
  unsigned u = __builtin_bit_cast(unsigned, f);
  return (u + 0x7fffu + ((u >> 16) & 1u)) >> 16;   // RTNE fp32->bf16
}

// cache-bypassing (agent/IF$-coherent) 16B load / 4B store
#define ALD(reg, off) \
  asm volatile("global_load_dwordx4 %0, %1, off offset:" #off " sc1" \
               : "=v"(reg) : "v"(ap))
#define PST(off, val) \
  asm volatile("global_store_dword %0, %1, off offset:" #off " sc1" \
               :: "v"(pp), "v"(val))

#define KSTEP(kt) \
  acc0 = __builtin_amdgcn_mfma_f32_16x16x32_bf16(a##kt, wf0[kt], acc0, 0, 0, 0); \
  acc1 = __builtin_amdgcn_mfma_f32_16x16x32_bf16(a##kt, wf1[kt], acc1, 0, 0, 0); \
  acc2 = __builtin_amdgcn_mfma_f32_16x16x32_bf16(a##kt, wf2[kt], acc2, 0, 0, 0);

__global__ void __launch_bounds__(128, 1) gru_phase1(
    const float* __restrict__ V,
    const float* __restrict__ W_ih,
    const float* __restrict__ W_hh,
    const float* __restrict__ b_ih,
    const float* __restrict__ b_hh,
    const float* __restrict__ Wr,
    float* __restrict__ res_all,      // [T][B][2] fp32, pre-zeroed
    unsigned* __restrict__ hbuf,      // [2][256][256] dwords (bf16 pairs)
    unsigned* __restrict__ flags)     // [16*32] waves * 16-dword stride
{
  const int tid   = threadIdx.x;
  const int w     = tid >> 6;          // wave 0/1 within wg
  const int lane  = tid & 63;
  const int g     = blockIdx.x & 15;   // batch group (16 rows)
  const int slice = blockIdx.x >> 4;   // 32-col slice

  const int cl  = lane & 15;           // col within 16
  const int hi4 = lane >> 4;           // k-quarter / C-row quarter
  const int c   = slice * 32 + w * 16 + cl;    // global h col owned by lane

  // ---- per-col pointwise constants ----
  const float wir0 = W_ih[c * 2 + 0],          wir1 = W_ih[c * 2 + 1];
  const float wiz0 = W_ih[(512 + c) * 2 + 0],  wiz1 = W_ih[(512 + c) * 2 + 1];
  const float win0 = W_ih[(1024 + c) * 2 + 0], win1 = W_ih[(1024 + c) * 2 + 1];
  const float bsr = b_ih[c] + b_hh[c];
  const float bsz = b_ih[512 + c] + b_hh[512 + c];
  const float bin = b_ih[1024 + c];
  const float bhn = b_hh[1024 + c];
  const float wr0 = Wr[c], wr1 = Wr[512 + c];

  // ---- B-fragments: 3 gates x 16 k-tiles, bf16, resident in VGPRs ----
  bf16x8 wf0[16], wf1[16], wf2[16];
  {
    const int brow = slice * 32 + w * 16 + cl;   // W_hh out-row within gate
    #pragma unroll
    for (int gt = 0; gt < 3; ++gt) {
      const float* src = W_hh + ((size_t)(gt * 512 + brow)) * 512 + hi4 * 8;
      #pragma unroll
      for (int kt = 0; kt < 16; ++kt) {
        float4 x = *reinterpret_cast<const float4*>(src + kt * 32);
        float4 y = *reinterpret_cast<const float4*>(src + kt * 32 + 4);
        bf16x8 t;
        t[0] = (short)f2bf(x.x); t[1] = (short)f2bf(x.y);
        t[2] = (short)f2bf(x.z); t[3] = (short)f2bf(x.w);
        t[4] = (short)f2bf(y.x); t[5] = (short)f2bf(y.y);
        t[6] = (short)f2bf(y.z); t[7] = (short)f2bf(y.w);
        if (gt == 0) wf0[kt] = t; else if (gt == 1) wf1[kt] = t; else wf2[kt] = t;
      }
    }
  }

  // ---- exchange-buffer addresses ----
  const char* hb = (const char*)hbuf;
  // A-frag: row = g*16 + cl (batch), k-offset = hi4*16 bytes, +64B per kt
  const unsigned aoff = (unsigned)(g * 16 + cl) * 1024u + (unsigned)hi4 * 16u;
  const char* ap0 = hb + aoff;
  const char* ap1 = hb + 262144 + aoff;
  // publish: even-cl lanes store dword (col pair) for 4 batch rows (j*1024B)
  const unsigned pub_off = (unsigned)(g * 16 + hi4 * 4) * 1024u + (unsigned)(c >> 1) * 4u;
  char* pub0 = (char*)hbuf + pub_off;
  char* pub1 = (char*)hbuf + 262144 + pub_off;

  unsigned* myflag = flags + (g * 32 + slice * 2 + w) * 16;
  unsigned* pollp  = flags + (g * 32 + (lane & 31)) * 16;

  float h0 = 0.f, h1 = 0.f, h2 = 0.f, h3 = 0.f;   // h state (4 rows x 1 col)

  for (int s = 0; s < 1024; ++s) {
    f32x4 acc0 = {0.f, 0.f, 0.f, 0.f};
    f32x4 acc1 = {0.f, 0.f, 0.f, 0.f};
    f32x4 acc2 = {0.f, 0.f, 0.f, 0.f};

    if (s > 0) {
      // ---- wait for all 32 producer-waves of this group @ step s ----
      int gd = 0;
      for (;;) {
        unsigned fv = __hip_atomic_load(pollp, __ATOMIC_RELAXED,
                                        __HIP_MEMORY_SCOPE_AGENT);
        if (__ballot(fv >= (unsigned)s) == ~0ull) break;
        if (++gd > (1 << 21)) break;   // hang insurance -> fast wrong answer
      }
      __builtin_amdgcn_sched_barrier(0);

      // ---- load A-frags (h(s-1), bf16) straight from IF$ ----
      const char* ap = ((s - 1) & 1) ? ap1 : ap0;
      bf16x8 a0,a1,a2,a3,a4,a5,a6,a7,a8,a9,a10,a11,a12,a13,a14,a15;
      ALD(a0, 0);    ALD(a1, 64);   ALD(a2, 128);  ALD(a3, 192);
      ALD(a4, 256);  ALD(a5, 320);  ALD(a6, 384);  ALD(a7, 448);
      ALD(a8, 512);  ALD(a9, 576);  ALD(a10, 640); ALD(a11, 704);
      ALD(a12, 768); ALD(a13, 832); ALD(a14, 896); ALD(a15, 960);
      asm volatile("s_waitcnt vmcnt(0)" ::: "memory");
      __builtin_amdgcn_sched_barrier(0);

      // ---- gh = h(s-1) @ Whh_slice^T : 3 independent 16-chains ----
      KSTEP(0)  KSTEP(1)  KSTEP(2)  KSTEP(3)
      KSTEP(4)  KSTEP(5)  KSTEP(6)  KSTEP(7)
      KSTEP(8)  KSTEP(9)  KSTEP(10) KSTEP(11)
      KSTEP(12) KSTEP(13) KSTEP(14) KSTEP(15)
    }

    // ---- pointwise GRU update: lane has r/z/n for (4 batch rows, col c) ----
    float hn_[4];
    const float hprev[4] = {h0, h1, h2, h3};
    #pragma unroll
    for (int j = 0; j < 4; ++j) {
      const int rj = g * 16 + hi4 * 4 + j;
      const float2 vv = *reinterpret_cast<const float2*>(&V[((size_t)rj * 1024 + s) * 2]);
      float pr = acc0[j] + bsr + wir0 * vv.x + wir1 * vv.y;
      float pz = acc1[j] + bsz + wiz0 * vv.x + wiz1 * vv.y;
      float rg = 1.f / (1.f + __expf(-pr));
      float zg = 1.f / (1.f + __expf(-pz));
      float pn = win0 * vv.x + win1 * vv.y + bin + rg * (acc2[j] + bhn);
      pn = fminf(fmaxf(pn, -30.f), 30.f);
      float e2 = __expf(2.f * pn);
      float tg = (e2 - 1.f) / (e2 + 1.f);
      hn_[j] = (1.f - zg) * tg + zg * hprev[j];
    }
    h0 = hn_[0]; h1 = hn_[1]; h2 = hn_[2]; h3 = hn_[3];

    // ---- publish h(s): pack col pairs, even-cl lanes store 4 dwords ----
    unsigned pk0, pk1, pk2, pk3;
    {
      float o0 = __shfl_xor(hn_[0], 1), o1 = __shfl_xor(hn_[1], 1);
      float o2 = __shfl_xor(hn_[2], 1), o3 = __shfl_xor(hn_[3], 1);
      pk0 = f2bf(hn_[0]) | (f2bf(o0) << 16);
      pk1 = f2bf(hn_[1]) | (f2bf(o1) << 16);
      pk2 = f2bf(hn_[2]) | (f2bf(o2) << 16);
      pk3 = f2bf(hn_[3]) | (f2bf(o3) << 16);
    }
    if (!(cl & 1)) {
      char* pp = (s & 1) ? pub1 : pub0;
      PST(0, pk0); PST(1024, pk1); PST(2048, pk2); PST(3072, pk3);
    }
    asm volatile("s_waitcnt vmcnt(0)" ::: "memory");
    __hip_atomic_store(myflag, (unsigned)(s + 1), __ATOMIC_RELEASE,
                       __HIP_MEMORY_SCOPE_AGENT);

    // ---- res partials (off critical path, after flag) ----
    float p0[4], p1[4];
    #pragma unroll
    for (int j = 0; j < 4; ++j) { p0[j] = wr0 * hn_[j]; p1[j] = wr1 * hn_[j]; }
    #pragma unroll
    for (int m = 1; m < 16; m <<= 1) {
      #pragma unroll
      for (int j = 0; j < 4; ++j) {
        p0[j] += __shfl_xor(p0[j], m);
        p1[j] += __shfl_xor(p1[j], m);
      }
    }
    if (cl == 0) {
      #pragma unroll
      for (int j = 0; j < 4; ++j) {
        const int rj = g * 16 + hi4 * 4 + j;
        atomicAdd(&res_all[((size_t)s * 256 + rj) * 2 + 0], p0[j]);
        atomicAdd(&res_all[((size_t)s * 256 + rj) * 2 + 1], p1[j]);
      }
    }
  }
}

// ---------------- Phase 2: correction scan (one wave per batch row) ----------
__global__ void __launch_bounds__(256) corr_phase2(
    const float* __restrict__ X0,
    const float* __restrict__ V,
    const float* __restrict__ Wa1,
    const float* __restrict__ ba1,
    const float* __restrict__ Wa2,
    const float* __restrict__ ba2,
    const float* __restrict__ br,
    const float* __restrict__ res_all,
    float* __restrict__ out)
{
  const int tid = threadIdx.x;
  const int wv = tid >> 6;
  const int lane = tid & 63;
  const int b = blockIdx.x * 4 + wv;

  float w1[4][4], bb1[4], w20[4], w21[4];
  #pragma unroll
  for (int q = 0; q < 4; q++) {
    const int h = lane * 4 + q;
    #pragma unroll
    for (int c = 0; c < 4; c++) w1[q][c] = Wa1[h * 4 + c];
    bb1[q] = ba1[h];
    w20[q] = Wa2[h];
    w21[q] = Wa2[256 + h];
  }
  const float c20 = ba2[0], c21 = ba2[1];
  const float br0 = br[0], br1 = br[1];
  float x0 = X0[b * 2], x1 = X0[b * 2 + 1];

  for (int c = 0; c < 16; c++) {
    const int tl = c * 64 + lane;
    const float2 vvl = *reinterpret_cast<const float2*>(&V[(b * 1024 + tl) * 2]);
    const float2 rrl = *reinterpret_cast<const float2*>(&res_all[(tl * 256 + b) * 2]);
    float sx = 0.f, sy = 0.f;
    for (int k = 0; k < 64; k++) {
      const float v0 = __shfl(vvl.x, k);
      const float v1 = __shfl(vvl.y, k);
      const float r0 = __shfl(rrl.x, k) + br0;
      const float r1 = __shfl(rrl.y, k) + br1;
      float l0 = 0.f, l1 = 0.f;
      #pragma unroll
      for (int q = 0; q < 4; q++) {
        float hq = w1[q][0] * x0 + w1[q][1] * x1 + w1[q][2] * v0 + w1[q][3] * v1 + bb1[q];
        hq = fmaxf(hq, 0.f);
        l0 += w20[q] * hq;
        l1 += w21[q] * hq;
      }
      #pragma unroll
      for (int m = 1; m < 64; m <<= 1) {
        l0 += __shfl_xor(l0, m);
        l1 += __shfl_xor(l1, m);
      }
      l0 += c20; l1 += c21;
      const float mx = fmaxf(l0, l1);
      const float e0 = __expf(l0 - mx), e1 = __expf(l1 - mx);
      const float inv = 1.f / (e0 + e1);
      x0 += v0 + (e0 * inv) * r0;
      x1 += v1 + (e1 * inv) * r1;
      if (k == lane) { sx = x0; sy = x1; }
    }
    float2 o; o.x = sx; o.y = sy;
    *reinterpret_cast<float2*>(&out[(b * 1024 + c * 64 + lane) * 2]) = o;
  }
}

extern "C" void kernel_launch(void* const* d_in, const int* in_sizes, int n_in,
                              void* d_out, int out_size, void* d_ws, size_t ws_size,
                              hipStream_t stream) {
  const float* X0   = (const float*)d_in[0];
  const float* V    = (const float*)d_in[1];
  const float* W_ih = (const float*)d_in[2];
  const float* W_hh = (const float*)d_in[3];
  const float* b_ih = (const float*)d_in[4];
  const float* b_hh = (const float*)d_in[5];
  const float* Wa1  = (const float*)d_in[6];
  const float* ba1  = (const float*)d_in[7];
  const float* Wa2  = (const float*)d_in[8];
  const float* ba2  = (const float*)d_in[9];
  const float* Wr   = (const float*)d_in[10];
  const float* br   = (const float*)d_in[11];
  float* out = (float*)d_out;

  char* ws = (char*)d_ws;
  float*    res_all = (float*)ws;                                     // 2 MB
  unsigned* hbuf    = (unsigned*)(ws + 2 * 1024 * 1024);              // 512 KB
  unsigned* flags   = (unsigned*)(ws + 2 * 1024 * 1024 + 512 * 1024); // 32 KB
  const size_t total = 2 * 1024 * 1024 + 512 * 1024 + 32 * 1024;
  hipMemsetAsync(d_ws, 0, total, stream);

  hipLaunchKernelGGL(gru_phase1, dim3(256), dim3(128), 0, stream,
                     V, W_ih, W_hh, b_ih, b_hh, Wr, res_all, hbuf, flags);
  hipLaunchKernelGGL(corr_phase2, dim3(64), dim3(256), 0, stream,
                     X0, V, Wa1, ba1, Wa2, ba2, br, res_all, out);
}